// Round 5
// baseline (242.829 us; speedup 1.0000x reference)
//
#include <hip/hip_runtime.h>

#define DEVFN __device__ __forceinline__

// NaN-propagating relu (fmaxf(NaN,0)==0 would mask upstream failures).
DEVFN float relu(float x) { return x < 0.f ? 0.f : x; }

// ---------------------------------------------------------------------------
// K13: fused K1+K3.
//   src = features@in_w + in_b + relu(vc@pe_w1+pe_b1)@pe_w2 + pe_b2
//   qs/ks/vs = src @ {q,k,v}_w   (no bias; applied at gather in K4)
//   packed coords (x | y<<8 | z<<16)
// block=256, 8 rows/block, 1024 blocks.
// ---------------------------------------------------------------------------
__global__ __launch_bounds__(256) void k13_src_qkv_cst(
    const float* __restrict__ features, const int* __restrict__ coords,
    const float* __restrict__ pe_w1, const float* __restrict__ pe_b1,
    const float* __restrict__ pe_w2, const float* __restrict__ pe_b2,
    const float* __restrict__ in_w, const float* __restrict__ in_b,
    const float* __restrict__ q_w, const float* __restrict__ k_w,
    const float* __restrict__ v_w,
    float* __restrict__ src, int* __restrict__ packed,
    float* __restrict__ qs, float* __restrict__ ks, float* __restrict__ vs)
{
    __shared__ float sF[512];   // 8 rows x 64 features
    __shared__ float sH[512];   // 8 rows x 64 pe-hidden
    __shared__ float S[1024];   // 8 rows x 128 src
    __shared__ int   sC[24];
    const int tid = threadIdx.x;
    const int r0 = blockIdx.x * 8;
    if (tid < 24) sC[tid] = coords[r0 * 3 + tid];
    for (int i = tid; i < 512; i += 256) sF[i] = features[r0 * 64 + i];
    __syncthreads();
    for (int i = tid; i < 512; i += 256) {
        int r = i >> 6, t = i & 63;
        float v0 = sC[r * 3 + 0] * (1.f / 95.f);
        float v1 = sC[r * 3 + 1] * (1.f / 95.f);
        float v2 = sC[r * 3 + 2] * (1.f / 95.f);
        float h = v0 * pe_w1[t] + v1 * pe_w1[64 + t] + v2 * pe_w1[128 + t] + pe_b1[t];
        sH[i] = relu(h);
    }
    __syncthreads();
    const int c = tid & 127, rh = tid >> 7;
    {
        float acc[4];
        const float base = in_b[c] + pe_b2[c];
#pragma unroll
        for (int r = 0; r < 4; ++r) acc[r] = base;
        const float* w1p = in_w + c;
        const float* w2p = pe_w2 + c;
#pragma unroll 4
        for (int j = 0; j < 64; ++j) {
            float w1 = w1p[j * 128];
            float w2 = w2p[j * 128];
#pragma unroll
            for (int r = 0; r < 4; ++r) {
                int rr = rh * 4 + r;
                acc[r] += sF[rr * 64 + j] * w1 + sH[rr * 64 + j] * w2;
            }
        }
#pragma unroll
        for (int r = 0; r < 4; ++r) {
            src[(r0 + rh * 4 + r) * 128 + c] = acc[r];
            S[(rh * 4 + r) * 128 + c] = acc[r];
        }
        if (tid < 8)
            packed[r0 + tid] = sC[tid * 3] | (sC[tid * 3 + 1] << 8) | (sC[tid * 3 + 2] << 16);
    }
    __syncthreads();
    // three projection passes over the LDS src tile
#pragma unroll
    for (int which = 0; which < 3; ++which) {
        const float* __restrict__ w = (which == 0) ? q_w : (which == 1) ? k_w : v_w;
        float* __restrict__ out = (which == 0) ? qs : (which == 1) ? ks : vs;
        float acc[4];
#pragma unroll
        for (int r = 0; r < 4; ++r) acc[r] = 0.f;
        const float* wp = w + c;
#pragma unroll 4
        for (int k4 = 0; k4 < 32; ++k4) {
            float w0 = wp[(k4 * 4 + 0) * 128];
            float w1 = wp[(k4 * 4 + 1) * 128];
            float w2 = wp[(k4 * 4 + 2) * 128];
            float w3 = wp[(k4 * 4 + 3) * 128];
#pragma unroll
            for (int r = 0; r < 4; ++r) {
                float4 s = *(const float4*)(&S[(rh * 4 + r) * 128 + k4 * 4]);
                acc[r] += s.x * w0 + s.y * w1 + s.z * w2 + s.w * w3;
            }
        }
#pragma unroll
        for (int r = 0; r < 4; ++r) out[(r0 + rh * 4 + r) * 128 + c] = acc[r];
    }
}

// ---------------------------------------------------------------------------
// K2: neighbor top-16 by (manhattan dist <=4, then index), stable; also zeros
// the BN accumulators (block 0). Rank-based selection, keys unique.
// ---------------------------------------------------------------------------
__global__ __launch_bounds__(256) void k2_nbr_cst(
    const int* __restrict__ packed, int* __restrict__ nbr,
    float* __restrict__ bnAcc, int N)
{
    __shared__ int pc[8192];
    __shared__ int cnt[16];
    __shared__ int lst[16 * 64];
    __shared__ int outL[256];
    const int tid = threadIdx.x;
    if (blockIdx.x == 0 && tid < 128) bnAcc[tid] = 0.f;
    for (int i = tid; i < N; i += 256) pc[i] = packed[i];
    if (tid < 16) cnt[tid] = 0;
    outL[tid] = -1;
    __syncthreads();
    const int q0 = blockIdx.x * 16;
    int qx[16], qy[16], qz[16];
#pragma unroll
    for (int q = 0; q < 16; ++q) {
        int p = pc[q0 + q];
        qx[q] = p & 255; qy[q] = (p >> 8) & 255; qz[q] = p >> 16;
    }
    for (int cd = tid; cd < N; cd += 256) {
        int p = pc[cd];
        int cx = p & 255, cy = (p >> 8) & 255, cz = p >> 16;
#pragma unroll
        for (int q = 0; q < 16; ++q) {
            int dx = cx - qx[q]; dx = dx < 0 ? -dx : dx;
            int dy = cy - qy[q]; dy = dy < 0 ? -dy : dy;
            int dz = cz - qz[q]; dz = dz < 0 ? -dz : dz;
            int d = dx + dy + dz;
            if (d <= 4) {
                int s = atomicAdd(&cnt[q], 1);
                if (s < 64) lst[q * 64 + s] = (d << 13) | cd;
            }
        }
    }
    __syncthreads();
    {
        const int q = tid >> 4, t = tid & 15;
        int n = cnt[q]; if (n > 64) n = 64;
        for (int e = t; e < n; e += 16) {
            int key = lst[q * 64 + e];
            int rank = 0;
            for (int j = 0; j < n; ++j) rank += (lst[q * 64 + j] < key) ? 1 : 0;
            if (rank < 16) outL[q * 16 + rank] = key & 8191;
        }
    }
    __syncthreads();
    {
        const int q = tid >> 4, t = tid & 15;
        nbr[(q0 + q) * 16 + t] = outL[q * 16 + t];
    }
}

// ---------------------------------------------------------------------------
// K4: attention (torch-view interleave) + o-proj + LN1 + FFN + LN2 + fusion
//     linear + BN partial sums. 8 rows/block, 1024 blocks.
// ---------------------------------------------------------------------------
DEVFN void ln_rows8(float* Cb, const float* __restrict__ g,
                    const float* __restrict__ b, int tid)
{
    const int r = tid >> 5, l = tid & 31;
    float x[4]; float s = 0.f, s2 = 0.f;
#pragma unroll
    for (int i = 0; i < 4; ++i) {
        x[i] = Cb[r * 128 + l * 4 + i];
        s += x[i]; s2 += x[i] * x[i];
    }
#pragma unroll
    for (int o = 1; o < 32; o <<= 1) { s += __shfl_xor(s, o); s2 += __shfl_xor(s2, o); }
    float mu = s * (1.f / 128.f);
    float var = s2 * (1.f / 128.f) - mu * mu;
    float rstd = rsqrtf(var + 1e-5f);
#pragma unroll
    for (int i = 0; i < 4; ++i) {
        int cc = l * 4 + i;
        Cb[r * 128 + cc] = (x[i] - mu) * rstd * g[cc] + b[cc];
    }
}

__global__ __launch_bounds__(256) void k4_main_cst(
    const float* __restrict__ features, const float* __restrict__ src,
    const float* __restrict__ qs, const float* __restrict__ ks, const float* __restrict__ vs,
    const int* __restrict__ nbr,
    const float* __restrict__ q_b, const float* __restrict__ k_b,
    const float* __restrict__ v_b,
    const float* __restrict__ o_w, const float* __restrict__ o_b,
    const float* __restrict__ n1_g, const float* __restrict__ n1_b,
    const float* __restrict__ l1_w, const float* __restrict__ l1_b,
    const float* __restrict__ l2_w, const float* __restrict__ l2_b,
    const float* __restrict__ n3_g, const float* __restrict__ n3_b,
    const float* __restrict__ fu_w, const float* __restrict__ fu_b,
    float* __restrict__ fused, float* __restrict__ bnSum, float* __restrict__ bnSq)
{
    __shared__ float A[1024];           // src tile (kept for residual)
    __shared__ float Bt[1024];          // head_out
    __shared__ float C[1024];           // running activation
    __shared__ float Q[1024];           // q rows (bias applied)
    __shared__ float H[2048];           // ffn hidden / bn staging
    __shared__ float SC[512];           // attention scores
    __shared__ float F[512];            // features tile
    __shared__ __align__(16) float bK[128], bV[128];
    __shared__ float bQ[128];
    __shared__ int idxL[128];
    const int tid = threadIdx.x;
    const int r0 = blockIdx.x * 8;

    for (int i = tid; i < 1024; i += 256) A[i] = src[r0 * 128 + i];
    for (int i = tid; i < 512; i += 256) F[i] = features[r0 * 64 + i];
    if (tid < 128) {
        idxL[tid] = nbr[r0 * 16 + tid];
        bQ[tid] = q_b[tid]; bK[tid] = k_b[tid]; bV[tid] = v_b[tid];
    }
    __syncthreads();
    for (int i = tid; i < 1024; i += 256) {
        int r = i >> 7, c = i & 127;
        int i0 = idxL[r * 16];
        Q[i] = (i0 < 0 ? 0.f : qs[i0 * 128 + c]) + bQ[c];
    }
    __syncthreads();

    // ---- phase 1a: scores. thread = (row r, head h, group g of 8) --------
    const int ar = tid >> 5, ah = (tid >> 3) & 3, ag = tid & 7;
    {
#pragma unroll
        for (int jj = 0; jj < 2; ++jj) {
            int j = ag + jj * 8;
            int j4 = j >> 2, ch = j & 3;
            int id = idxL[ar * 16 + ah * 4 + j4];
            float s = 0.f;
#pragma unroll
            for (int c4 = 0; c4 < 8; ++c4) {
                float4 qv = *(const float4*)(&Q[ar * 128 + ah * 32 + c4 * 4]);
                float4 kb = *(const float4*)(&bK[ch * 32 + c4 * 4]);
                float4 kv = make_float4(0.f, 0.f, 0.f, 0.f);
                if (id >= 0) kv = *(const float4*)(ks + id * 128 + ch * 32 + c4 * 4);
                s += qv.x * (kv.x + kb.x) + qv.y * (kv.y + kb.y)
                   + qv.z * (kv.z + kb.z) + qv.w * (kv.w + kb.w);
            }
            SC[ar * 64 + ah * 16 + j] = s * 0.08838834764831845f;  // 1/sqrt(128)
        }
    }
    __syncthreads();

    // ---- phase 1b: softmax (redundant per 8-thread group) + P@V ----------
    {
        float p[16];
        float mx = -3.4e38f;
#pragma unroll
        for (int j = 0; j < 16; ++j) { p[j] = SC[ar * 64 + ah * 16 + j]; mx = fmaxf(mx, p[j]); }
        float sum = 0.f;
#pragma unroll
        for (int j = 0; j < 16; ++j) { p[j] = __expf(p[j] - mx); sum += p[j]; }
        float inv = 1.f / sum;
        float4 acc = make_float4(0.f, 0.f, 0.f, 0.f);
#pragma unroll
        for (int j = 0; j < 16; ++j) {
            int j4 = j >> 2, ch = j & 3;
            int id = idxL[ar * 16 + ah * 4 + j4];
            float4 vb = *(const float4*)(&bV[ch * 32 + ag * 4]);
            float4 vv = make_float4(0.f, 0.f, 0.f, 0.f);
            if (id >= 0) vv = *(const float4*)(vs + id * 128 + ch * 32 + ag * 4);
            float w = p[j] * inv;
            acc.x += w * (vv.x + vb.x); acc.y += w * (vv.y + vb.y);
            acc.z += w * (vv.z + vb.z); acc.w += w * (vv.w + vb.w);
        }
        *(float4*)(&Bt[ar * 128 + ah * 32 + ag * 4]) = acc;
    }
    __syncthreads();

    // ---- phase 2: C = A + head_out @ o_w + o_b ---------------------------
    {
        const int c = tid & 127, rh = tid >> 7;
        float acc[4];
        const float ob = o_b[c];
#pragma unroll
        for (int r = 0; r < 4; ++r) acc[r] = ob;
        const float* wp = o_w + c;
#pragma unroll 4
        for (int k4 = 0; k4 < 32; ++k4) {
            float w0 = wp[(k4 * 4 + 0) * 128];
            float w1 = wp[(k4 * 4 + 1) * 128];
            float w2 = wp[(k4 * 4 + 2) * 128];
            float w3 = wp[(k4 * 4 + 3) * 128];
#pragma unroll
            for (int r = 0; r < 4; ++r) {
                float4 t = *(const float4*)(&Bt[(rh * 4 + r) * 128 + k4 * 4]);
                acc[r] += t.x * w0 + t.y * w1 + t.z * w2 + t.w * w3;
            }
        }
#pragma unroll
        for (int r = 0; r < 4; ++r) {
            int row = rh * 4 + r;
            C[row * 128 + c] = A[row * 128 + c] + acc[r];
        }
    }
    __syncthreads();
    ln_rows8(C, n1_g, n1_b, tid);   // C = tgt
    __syncthreads();

    // ---- phase 3: H = relu(C @ l1_w + l1_b)  [8 x 256] -------------------
    {
        const int f = tid;
        float acc[8];
#pragma unroll
        for (int r = 0; r < 8; ++r) acc[r] = 0.f;
        const float* wp = l1_w + f;
#pragma unroll 4
        for (int k4 = 0; k4 < 32; ++k4) {
            float w0 = wp[(k4 * 4 + 0) * 256];
            float w1 = wp[(k4 * 4 + 1) * 256];
            float w2 = wp[(k4 * 4 + 2) * 256];
            float w3 = wp[(k4 * 4 + 3) * 256];
#pragma unroll
            for (int r = 0; r < 8; ++r) {
                float4 t = *(const float4*)(&C[r * 128 + k4 * 4]);
                acc[r] += t.x * w0 + t.y * w1 + t.z * w2 + t.w * w3;
            }
        }
        const float bb = l1_b[f];
#pragma unroll
        for (int r = 0; r < 8; ++r) H[r * 256 + f] = relu(acc[r] + bb);
    }
    __syncthreads();

    // ---- phase 4: C += H @ l2_w + l2_b -----------------------------------
    {
        const int c = tid & 127, rh = tid >> 7;
        float acc[4];
        const float lb = l2_b[c];
#pragma unroll
        for (int r = 0; r < 4; ++r) acc[r] = lb;
        const float* wp = l2_w + c;
#pragma unroll 4
        for (int k4 = 0; k4 < 64; ++k4) {
            float w0 = wp[(k4 * 4 + 0) * 128];
            float w1 = wp[(k4 * 4 + 1) * 128];
            float w2 = wp[(k4 * 4 + 2) * 128];
            float w3 = wp[(k4 * 4 + 3) * 128];
#pragma unroll
            for (int r = 0; r < 4; ++r) {
                float4 t = *(const float4*)(&H[(rh * 4 + r) * 256 + k4 * 4]);
                acc[r] += t.x * w0 + t.y * w1 + t.z * w2 + t.w * w3;
            }
        }
#pragma unroll
        for (int r = 0; r < 4; ++r) {
            int row = rh * 4 + r;
            C[row * 128 + c] += acc[r];
        }
    }
    __syncthreads();
    ln_rows8(C, n3_g, n3_b, tid);   // C = final tgt
    __syncthreads();

    // ---- phase 5: fused = [F, C] @ fu_w + fu_b; BN partials --------------
    {
        const int c = tid & 63, rg = tid >> 6;
        float acc[2];
        const float fb = fu_b[c];
#pragma unroll
        for (int r = 0; r < 2; ++r) acc[r] = fb;
        const float* wp = fu_w + c;
#pragma unroll 4
        for (int j4 = 0; j4 < 16; ++j4) {
            float w0 = wp[(j4 * 4 + 0) * 64];
            float w1 = wp[(j4 * 4 + 1) * 64];
            float w2 = wp[(j4 * 4 + 2) * 64];
            float w3 = wp[(j4 * 4 + 3) * 64];
#pragma unroll
            for (int r = 0; r < 2; ++r) {
                float4 t = *(const float4*)(&F[(rg * 2 + r) * 64 + j4 * 4]);
                acc[r] += t.x * w0 + t.y * w1 + t.z * w2 + t.w * w3;
            }
        }
        const float* wp2 = fu_w + 64 * 64 + c;
#pragma unroll 4
        for (int j4 = 0; j4 < 32; ++j4) {
            float w0 = wp2[(j4 * 4 + 0) * 64];
            float w1 = wp2[(j4 * 4 + 1) * 64];
            float w2 = wp2[(j4 * 4 + 2) * 64];
            float w3 = wp2[(j4 * 4 + 3) * 64];
#pragma unroll
            for (int r = 0; r < 2; ++r) {
                float4 t = *(const float4*)(&C[(rg * 2 + r) * 128 + j4 * 4]);
                acc[r] += t.x * w0 + t.y * w1 + t.z * w2 + t.w * w3;
            }
        }
#pragma unroll
        for (int r = 0; r < 2; ++r) {
            int row = rg * 2 + r;
            float v = acc[r];
            fused[(r0 + row) * 64 + c] = v;
            H[row * 64 + c] = v;
        }
    }
    __syncthreads();
    if (tid < 64) {
        float s = 0.f, s2 = 0.f;
#pragma unroll
        for (int r = 0; r < 8; ++r) { float x = H[r * 64 + tid]; s += x; s2 += x * x; }
        atomicAdd(&bnSum[tid], s);
        atomicAdd(&bnSq[tid], s2);
    }
}

// ---------------------------------------------------------------------------
// K5: batchnorm (train-mode stats) + relu -> fp32 out
// ---------------------------------------------------------------------------
__global__ __launch_bounds__(256) void k5_bn_cst(
    const float* __restrict__ fused, const float* __restrict__ bnSum,
    const float* __restrict__ bnSq,
    const float* __restrict__ g, const float* __restrict__ b,
    float* __restrict__ out, int N)
{
    const int total = N * 64;
    const float invN = 1.f / (float)N;
    for (int i = blockIdx.x * 256 + threadIdx.x; i < total; i += gridDim.x * 256) {
        int c = i & 63;
        float mu = bnSum[c] * invN;
        float var = bnSq[c] * invN - mu * mu;
        float x = fused[i];
        float y = (x - mu) * rsqrtf(var + 1e-3f) * g[c] + b[c];
        out[i] = relu(y);
    }
}

// ---------------------------------------------------------------------------
extern "C" void kernel_launch(void* const* d_in, const int* in_sizes, int n_in,
                              void* d_out, int out_size, void* d_ws, size_t ws_size,
                              hipStream_t stream)
{
    const float* features = (const float*)d_in[0];
    const int*   coords   = (const int*)d_in[1];
    const float* pe_w1 = (const float*)d_in[2];
    const float* pe_b1 = (const float*)d_in[3];
    const float* pe_w2 = (const float*)d_in[4];
    const float* pe_b2 = (const float*)d_in[5];
    const float* in_w  = (const float*)d_in[6];
    const float* in_b  = (const float*)d_in[7];
    const float* q_w   = (const float*)d_in[8];
    const float* q_b   = (const float*)d_in[9];
    const float* k_w   = (const float*)d_in[10];
    const float* k_b   = (const float*)d_in[11];
    const float* v_w   = (const float*)d_in[12];
    const float* v_b   = (const float*)d_in[13];
    const float* o_w   = (const float*)d_in[14];
    const float* o_b   = (const float*)d_in[15];
    const float* n1_g  = (const float*)d_in[16];
    const float* n1_b  = (const float*)d_in[17];
    const float* l1_w  = (const float*)d_in[18];
    const float* l1_b  = (const float*)d_in[19];
    const float* l2_w  = (const float*)d_in[20];
    const float* l2_b  = (const float*)d_in[21];
    const float* n3_g  = (const float*)d_in[22];
    const float* n3_b  = (const float*)d_in[23];
    const float* fu_w  = (const float*)d_in[24];
    const float* fu_b  = (const float*)d_in[25];
    const float* bn_g  = (const float*)d_in[26];
    const float* bn_b  = (const float*)d_in[27];

    const int N = in_sizes[0] / 64;   // 8192

    float* src   = (float*)d_ws;            // N*128
    float* qs    = src + (size_t)N * 128;   // N*128
    float* ks    = qs  + (size_t)N * 128;   // N*128
    float* vs    = ks  + (size_t)N * 128;   // N*128
    float* fused = vs  + (size_t)N * 128;   // N*64
    int*   packed = (int*)(fused + (size_t)N * 64);   // N ints
    int*   nbr    = packed + N;                       // N*16 ints
    float* bnSum  = (float*)(nbr + (size_t)N * 16);   // 64
    float* bnSq   = bnSum + 64;                       // 64  (bnSum..bnSq contiguous 128)

    k13_src_qkv_cst<<<N / 8, 256, 0, stream>>>(features, coords, pe_w1, pe_b1,
                                               pe_w2, pe_b2, in_w, in_b,
                                               q_w, k_w, v_w,
                                               src, packed, qs, ks, vs);
    k2_nbr_cst<<<N / 16, 256, 0, stream>>>(packed, nbr, bnSum, N);
    k4_main_cst<<<N / 8, 256, 0, stream>>>(features, src, qs, ks, vs, nbr,
                                           q_b, k_b, v_b, o_w, o_b, n1_g, n1_b,
                                           l1_w, l1_b, l2_w, l2_b, n3_g, n3_b,
                                           fu_w, fu_b, fused, bnSum, bnSq);
    k5_bn_cst<<<512, 256, 0, stream>>>(fused, bnSum, bnSq, bn_g, bn_b,
                                       (float*)d_out, N);
}

// Round 6
// 228.065 us; speedup vs baseline: 1.0647x; 1.0647x over previous
//
#include <hip/hip_runtime.h>

#define DEVFN __device__ __forceinline__

// NaN-propagating relu (fmaxf(NaN,0)==0 would mask upstream failures).
DEVFN float relu(float x) { return x < 0.f ? 0.f : x; }

// ---------------------------------------------------------------------------
// KA: fused pre-work, two block roles in one dispatch.
//  blocks [0, N/8)          : src = features@in_w+in_b + relu(pe)@pe_w2+pe_b2
//                             qs/ks/vs = src @ {q,k,v}_w (interleaved streams)
//  blocks [N/8, N/8+N/16)   : neighbor top-16 (manhattan<=4, stable) from
//                             coords directly; block N/8 zeros BN accum.
// ---------------------------------------------------------------------------
__global__ __launch_bounds__(256) void ka_pre_cst(
    const float* __restrict__ features, const int* __restrict__ coords,
    const float* __restrict__ pe_w1, const float* __restrict__ pe_b1,
    const float* __restrict__ pe_w2, const float* __restrict__ pe_b2,
    const float* __restrict__ in_w, const float* __restrict__ in_b,
    const float* __restrict__ q_w, const float* __restrict__ k_w,
    const float* __restrict__ v_w,
    float* __restrict__ src,
    float* __restrict__ qs, float* __restrict__ ks, float* __restrict__ vs,
    int* __restrict__ nbr, float* __restrict__ bnAcc, int N)
{
    // K13-role LDS
    __shared__ float sF[512];   // 8 rows x 64 features
    __shared__ float sH[512];   // 8 rows x 64 pe-hidden
    __shared__ float S[1024];   // 8 rows x 128 src
    __shared__ int   sC[24];
    // K2-role LDS
    __shared__ int cnt[16];
    __shared__ int lst[16 * 64];
    __shared__ int outL[256];

    const int tid = threadIdx.x;
    const int nSrcBlocks = N / 8;

    if ((int)blockIdx.x >= nSrcBlocks) {
        // ---------------- K2 role: neighbor search -----------------------
        const int nb = blockIdx.x - nSrcBlocks;
        const int q0 = nb * 16;
        if (nb == 0 && tid < 128) bnAcc[tid] = 0.f;
        if (tid < 16) cnt[tid] = 0;
        outL[tid] = -1;
        __syncthreads();
        int qx[16], qy[16], qz[16];
#pragma unroll
        for (int q = 0; q < 16; ++q) {
            qx[q] = coords[(q0 + q) * 3 + 0];
            qy[q] = coords[(q0 + q) * 3 + 1];
            qz[q] = coords[(q0 + q) * 3 + 2];
        }
        for (int cd = tid; cd < N; cd += 256) {
            int cx = coords[cd * 3 + 0];
            int cy = coords[cd * 3 + 1];
            int cz = coords[cd * 3 + 2];
#pragma unroll
            for (int q = 0; q < 16; ++q) {
                int dx = cx - qx[q]; dx = dx < 0 ? -dx : dx;
                int dy = cy - qy[q]; dy = dy < 0 ? -dy : dy;
                int dz = cz - qz[q]; dz = dz < 0 ? -dz : dz;
                int d = dx + dy + dz;
                if (d <= 4) {
                    int s = atomicAdd(&cnt[q], 1);
                    if (s < 64) lst[q * 64 + s] = (d << 13) | cd;
                }
            }
        }
        __syncthreads();
        {
            const int q = tid >> 4, t = tid & 15;
            int n = cnt[q]; if (n > 64) n = 64;
            for (int e = t; e < n; e += 16) {
                int key = lst[q * 64 + e];
                int rank = 0;
                for (int j = 0; j < n; ++j) rank += (lst[q * 64 + j] < key) ? 1 : 0;
                if (rank < 16) outL[q * 16 + rank] = key & 8191;
            }
        }
        __syncthreads();
        {
            const int q = tid >> 4, t = tid & 15;
            nbr[(q0 + q) * 16 + t] = outL[q * 16 + t];
        }
        return;
    }

    // ---------------- K13 role: src + q/k/v projections -------------------
    const int r0 = blockIdx.x * 8;
    if (tid < 24) sC[tid] = coords[r0 * 3 + tid];
    for (int i = tid; i < 512; i += 256) sF[i] = features[r0 * 64 + i];
    __syncthreads();
    for (int i = tid; i < 512; i += 256) {
        int r = i >> 6, t = i & 63;
        float v0 = sC[r * 3 + 0] * (1.f / 95.f);
        float v1 = sC[r * 3 + 1] * (1.f / 95.f);
        float v2 = sC[r * 3 + 2] * (1.f / 95.f);
        float h = v0 * pe_w1[t] + v1 * pe_w1[64 + t] + v2 * pe_w1[128 + t] + pe_b1[t];
        sH[i] = relu(h);
    }
    __syncthreads();
    const int c = tid & 127, rh = tid >> 7;
    {
        float acc[4];
        const float base = in_b[c] + pe_b2[c];
#pragma unroll
        for (int r = 0; r < 4; ++r) acc[r] = base;
        for (int j = 0; j < 64; ++j) {
            float w1 = in_w[j * 128 + c];
            float w2 = pe_w2[j * 128 + c];
#pragma unroll
            for (int r = 0; r < 4; ++r) {
                int rr = rh * 4 + r;
                acc[r] += sF[rr * 64 + j] * w1 + sH[rr * 64 + j] * w2;
            }
        }
#pragma unroll
        for (int r = 0; r < 4; ++r) {
            src[(r0 + rh * 4 + r) * 128 + c] = acc[r];
            S[(rh * 4 + r) * 128 + c] = acc[r];
        }
    }
    __syncthreads();
    // q/k/v in one pass: 12 concurrent weight streams for latency hiding
    {
        float aq[4], ak[4], av[4];
#pragma unroll
        for (int r = 0; r < 4; ++r) { aq[r] = 0.f; ak[r] = 0.f; av[r] = 0.f; }
        for (int k4 = 0; k4 < 32; ++k4) {
            float wq0 = q_w[(k4 * 4 + 0) * 128 + c];
            float wq1 = q_w[(k4 * 4 + 1) * 128 + c];
            float wq2 = q_w[(k4 * 4 + 2) * 128 + c];
            float wq3 = q_w[(k4 * 4 + 3) * 128 + c];
            float wk0 = k_w[(k4 * 4 + 0) * 128 + c];
            float wk1 = k_w[(k4 * 4 + 1) * 128 + c];
            float wk2 = k_w[(k4 * 4 + 2) * 128 + c];
            float wk3 = k_w[(k4 * 4 + 3) * 128 + c];
            float wv0 = v_w[(k4 * 4 + 0) * 128 + c];
            float wv1 = v_w[(k4 * 4 + 1) * 128 + c];
            float wv2 = v_w[(k4 * 4 + 2) * 128 + c];
            float wv3 = v_w[(k4 * 4 + 3) * 128 + c];
#pragma unroll
            for (int r = 0; r < 4; ++r) {
                float4 s = *(const float4*)(&S[(rh * 4 + r) * 128 + k4 * 4]);
                aq[r] += s.x * wq0 + s.y * wq1 + s.z * wq2 + s.w * wq3;
                ak[r] += s.x * wk0 + s.y * wk1 + s.z * wk2 + s.w * wk3;
                av[r] += s.x * wv0 + s.y * wv1 + s.z * wv2 + s.w * wv3;
            }
        }
#pragma unroll
        for (int r = 0; r < 4; ++r) {
            qs[(r0 + rh * 4 + r) * 128 + c] = aq[r];
            ks[(r0 + rh * 4 + r) * 128 + c] = ak[r];
            vs[(r0 + rh * 4 + r) * 128 + c] = av[r];
        }
    }
}

// ---------------------------------------------------------------------------
// K4: attention (torch-view interleave) + o-proj + LN1 + FFN + LN2 + fusion
//     linear + BN partial sums. 8 rows/block, 1024 blocks.
// ---------------------------------------------------------------------------
DEVFN void ln_rows8(float* Cb, const float* __restrict__ g,
                    const float* __restrict__ b, int tid)
{
    const int r = tid >> 5, l = tid & 31;
    float x[4]; float s = 0.f, s2 = 0.f;
#pragma unroll
    for (int i = 0; i < 4; ++i) {
        x[i] = Cb[r * 128 + l * 4 + i];
        s += x[i]; s2 += x[i] * x[i];
    }
#pragma unroll
    for (int o = 1; o < 32; o <<= 1) { s += __shfl_xor(s, o); s2 += __shfl_xor(s2, o); }
    float mu = s * (1.f / 128.f);
    float var = s2 * (1.f / 128.f) - mu * mu;
    float rstd = rsqrtf(var + 1e-5f);
#pragma unroll
    for (int i = 0; i < 4; ++i) {
        int cc = l * 4 + i;
        Cb[r * 128 + cc] = (x[i] - mu) * rstd * g[cc] + b[cc];
    }
}

__global__ __launch_bounds__(256) void k4_main_cst(
    const float* __restrict__ features, const float* __restrict__ src,
    const float* __restrict__ qs, const float* __restrict__ ks, const float* __restrict__ vs,
    const int* __restrict__ nbr,
    const float* __restrict__ q_b, const float* __restrict__ k_b,
    const float* __restrict__ v_b,
    const float* __restrict__ o_w, const float* __restrict__ o_b,
    const float* __restrict__ n1_g, const float* __restrict__ n1_b,
    const float* __restrict__ l1_w, const float* __restrict__ l1_b,
    const float* __restrict__ l2_w, const float* __restrict__ l2_b,
    const float* __restrict__ n3_g, const float* __restrict__ n3_b,
    const float* __restrict__ fu_w, const float* __restrict__ fu_b,
    float* __restrict__ fused, float* __restrict__ bnSum, float* __restrict__ bnSq)
{
    __shared__ float A[1024];           // src tile (kept for residual)
    __shared__ float Bt[1024];          // head_out
    __shared__ float C[1024];           // running activation
    __shared__ float Q[1024];           // q rows (bias applied)
    __shared__ float H[2048];           // ffn hidden / bn staging
    __shared__ float SC[512];           // attention scores
    __shared__ float F[512];            // features tile
    __shared__ __align__(16) float bK[128], bV[128];
    __shared__ float bQ[128];
    __shared__ int idxL[128];
    const int tid = threadIdx.x;
    const int r0 = blockIdx.x * 8;

    for (int i = tid; i < 1024; i += 256) A[i] = src[r0 * 128 + i];
    for (int i = tid; i < 512; i += 256) F[i] = features[r0 * 64 + i];
    if (tid < 128) {
        idxL[tid] = nbr[r0 * 16 + tid];
        bQ[tid] = q_b[tid]; bK[tid] = k_b[tid]; bV[tid] = v_b[tid];
    }
    __syncthreads();
    for (int i = tid; i < 1024; i += 256) {
        int r = i >> 7, c = i & 127;
        int i0 = idxL[r * 16];
        Q[i] = (i0 < 0 ? 0.f : qs[i0 * 128 + c]) + bQ[c];
    }
    __syncthreads();

    // ---- phase 1a: scores. thread = (row r, head h, group g of 8) --------
    const int ar = tid >> 5, ah = (tid >> 3) & 3, ag = tid & 7;
    {
#pragma unroll
        for (int jj = 0; jj < 2; ++jj) {
            int j = ag + jj * 8;
            int j4 = j >> 2, ch = j & 3;
            int id = idxL[ar * 16 + ah * 4 + j4];
            float s = 0.f;
#pragma unroll
            for (int c4 = 0; c4 < 8; ++c4) {
                float4 qv = *(const float4*)(&Q[ar * 128 + ah * 32 + c4 * 4]);
                float4 kb = *(const float4*)(&bK[ch * 32 + c4 * 4]);
                float4 kv = make_float4(0.f, 0.f, 0.f, 0.f);
                if (id >= 0) kv = *(const float4*)(ks + id * 128 + ch * 32 + c4 * 4);
                s += qv.x * (kv.x + kb.x) + qv.y * (kv.y + kb.y)
                   + qv.z * (kv.z + kb.z) + qv.w * (kv.w + kb.w);
            }
            SC[ar * 64 + ah * 16 + j] = s * 0.08838834764831845f;  // 1/sqrt(128)
        }
    }
    __syncthreads();

    // ---- phase 1b: softmax (redundant per 8-thread group) + P@V ----------
    {
        float p[16];
        float mx = -3.4e38f;
#pragma unroll
        for (int j = 0; j < 16; ++j) { p[j] = SC[ar * 64 + ah * 16 + j]; mx = fmaxf(mx, p[j]); }
        float sum = 0.f;
#pragma unroll
        for (int j = 0; j < 16; ++j) { p[j] = __expf(p[j] - mx); sum += p[j]; }
        float inv = 1.f / sum;
        float4 acc = make_float4(0.f, 0.f, 0.f, 0.f);
#pragma unroll
        for (int j = 0; j < 16; ++j) {
            int j4 = j >> 2, ch = j & 3;
            int id = idxL[ar * 16 + ah * 4 + j4];
            float4 vb = *(const float4*)(&bV[ch * 32 + ag * 4]);
            float4 vv = make_float4(0.f, 0.f, 0.f, 0.f);
            if (id >= 0) vv = *(const float4*)(vs + id * 128 + ch * 32 + ag * 4);
            float w = p[j] * inv;
            acc.x += w * (vv.x + vb.x); acc.y += w * (vv.y + vb.y);
            acc.z += w * (vv.z + vb.z); acc.w += w * (vv.w + vb.w);
        }
        *(float4*)(&Bt[ar * 128 + ah * 32 + ag * 4]) = acc;
    }
    __syncthreads();

    // ---- phase 2: C = A + head_out @ o_w + o_b ---------------------------
    {
        const int c = tid & 127, rh = tid >> 7;
        float acc[4];
        const float ob = o_b[c];
#pragma unroll
        for (int r = 0; r < 4; ++r) acc[r] = ob;
        for (int k4 = 0; k4 < 32; ++k4) {
            float w0 = o_w[(k4 * 4 + 0) * 128 + c];
            float w1 = o_w[(k4 * 4 + 1) * 128 + c];
            float w2 = o_w[(k4 * 4 + 2) * 128 + c];
            float w3 = o_w[(k4 * 4 + 3) * 128 + c];
#pragma unroll
            for (int r = 0; r < 4; ++r) {
                float4 t = *(const float4*)(&Bt[(rh * 4 + r) * 128 + k4 * 4]);
                acc[r] += t.x * w0 + t.y * w1 + t.z * w2 + t.w * w3;
            }
        }
#pragma unroll
        for (int r = 0; r < 4; ++r) {
            int row = rh * 4 + r;
            C[row * 128 + c] = A[row * 128 + c] + acc[r];
        }
    }
    __syncthreads();
    ln_rows8(C, n1_g, n1_b, tid);   // C = tgt
    __syncthreads();

    // ---- phase 3: H = relu(C @ l1_w + l1_b)  [8 x 256] -------------------
    {
        const int f = tid;
        float acc[8];
#pragma unroll
        for (int r = 0; r < 8; ++r) acc[r] = 0.f;
        for (int k4 = 0; k4 < 32; ++k4) {
            float w0 = l1_w[(k4 * 4 + 0) * 256 + f];
            float w1 = l1_w[(k4 * 4 + 1) * 256 + f];
            float w2 = l1_w[(k4 * 4 + 2) * 256 + f];
            float w3 = l1_w[(k4 * 4 + 3) * 256 + f];
#pragma unroll
            for (int r = 0; r < 8; ++r) {
                float4 t = *(const float4*)(&C[r * 128 + k4 * 4]);
                acc[r] += t.x * w0 + t.y * w1 + t.z * w2 + t.w * w3;
            }
        }
        const float bb = l1_b[f];
#pragma unroll
        for (int r = 0; r < 8; ++r) H[r * 256 + f] = relu(acc[r] + bb);
    }
    __syncthreads();

    // ---- phase 4: C += H @ l2_w + l2_b -----------------------------------
    {
        const int c = tid & 127, rh = tid >> 7;
        float acc[4];
        const float lb = l2_b[c];
#pragma unroll
        for (int r = 0; r < 4; ++r) acc[r] = lb;
        for (int k4 = 0; k4 < 64; ++k4) {
            float w0 = l2_w[(k4 * 4 + 0) * 128 + c];
            float w1 = l2_w[(k4 * 4 + 1) * 128 + c];
            float w2 = l2_w[(k4 * 4 + 2) * 128 + c];
            float w3 = l2_w[(k4 * 4 + 3) * 128 + c];
#pragma unroll
            for (int r = 0; r < 4; ++r) {
                float4 t = *(const float4*)(&H[(rh * 4 + r) * 256 + k4 * 4]);
                acc[r] += t.x * w0 + t.y * w1 + t.z * w2 + t.w * w3;
            }
        }
#pragma unroll
        for (int r = 0; r < 4; ++r) {
            int row = rh * 4 + r;
            C[row * 128 + c] += acc[r];
        }
    }
    __syncthreads();
    ln_rows8(C, n3_g, n3_b, tid);   // C = final tgt
    __syncthreads();

    // ---- phase 5: fused = [F, C] @ fu_w + fu_b; BN partials --------------
    {
        const int c = tid & 63, rg = tid >> 6;
        float acc[2];
        const float fb = fu_b[c];
#pragma unroll
        for (int r = 0; r < 2; ++r) acc[r] = fb;
        for (int j4 = 0; j4 < 16; ++j4) {
            float w0 = fu_w[(j4 * 4 + 0) * 64 + c];
            float w1 = fu_w[(j4 * 4 + 1) * 64 + c];
            float w2 = fu_w[(j4 * 4 + 2) * 64 + c];
            float w3 = fu_w[(j4 * 4 + 3) * 64 + c];
#pragma unroll
            for (int r = 0; r < 2; ++r) {
                float4 t = *(const float4*)(&F[(rg * 2 + r) * 64 + j4 * 4]);
                acc[r] += t.x * w0 + t.y * w1 + t.z * w2 + t.w * w3;
            }
        }
        for (int j4 = 0; j4 < 32; ++j4) {
            float w0 = fu_w[(64 + j4 * 4 + 0) * 64 + c];
            float w1 = fu_w[(64 + j4 * 4 + 1) * 64 + c];
            float w2 = fu_w[(64 + j4 * 4 + 2) * 64 + c];
            float w3 = fu_w[(64 + j4 * 4 + 3) * 64 + c];
#pragma unroll
            for (int r = 0; r < 2; ++r) {
                float4 t = *(const float4*)(&C[(rg * 2 + r) * 128 + j4 * 4]);
                acc[r] += t.x * w0 + t.y * w1 + t.z * w2 + t.w * w3;
            }
        }
#pragma unroll
        for (int r = 0; r < 2; ++r) {
            int row = rg * 2 + r;
            float v = acc[r];
            fused[(r0 + row) * 64 + c] = v;
            H[row * 64 + c] = v;
        }
    }
    __syncthreads();
    if (tid < 64) {
        float s = 0.f, s2 = 0.f;
#pragma unroll
        for (int r = 0; r < 8; ++r) { float x = H[r * 64 + tid]; s += x; s2 += x * x; }
        atomicAdd(&bnSum[tid], s);
        atomicAdd(&bnSq[tid], s2);
    }
}

// ---------------------------------------------------------------------------
// K5: batchnorm (train-mode stats) + relu -> fp32 out
// ---------------------------------------------------------------------------
__global__ __launch_bounds__(256) void k5_bn_cst(
    const float* __restrict__ fused, const float* __restrict__ bnSum,
    const float* __restrict__ bnSq,
    const float* __restrict__ g, const float* __restrict__ b,
    float* __restrict__ out, int N)
{
    const int total = N * 64;
    const float invN = 1.f / (float)N;
    for (int i = blockIdx.x * 256 + threadIdx.x; i < total; i += gridDim.x * 256) {
        int c = i & 63;
        float mu = bnSum[c] * invN;
        float var = bnSq[c] * invN - mu * mu;
        float x = fused[i];
        float y = (x - mu) * rsqrtf(var + 1e-3f) * g[c] + b[c];
        out[i] = relu(y);
    }
}

// ---------------------------------------------------------------------------
extern "C" void kernel_launch(void* const* d_in, const int* in_sizes, int n_in,
                              void* d_out, int out_size, void* d_ws, size_t ws_size,
                              hipStream_t stream)
{
    const float* features = (const float*)d_in[0];
    const int*   coords   = (const int*)d_in[1];
    const float* pe_w1 = (const float*)d_in[2];
    const float* pe_b1 = (const float*)d_in[3];
    const float* pe_w2 = (const float*)d_in[4];
    const float* pe_b2 = (const float*)d_in[5];
    const float* in_w  = (const float*)d_in[6];
    const float* in_b  = (const float*)d_in[7];
    const float* q_w   = (const float*)d_in[8];
    const float* q_b   = (const float*)d_in[9];
    const float* k_w   = (const float*)d_in[10];
    const float* k_b   = (const float*)d_in[11];
    const float* v_w   = (const float*)d_in[12];
    const float* v_b   = (const float*)d_in[13];
    const float* o_w   = (const float*)d_in[14];
    const float* o_b   = (const float*)d_in[15];
    const float* n1_g  = (const float*)d_in[16];
    const float* n1_b  = (const float*)d_in[17];
    const float* l1_w  = (const float*)d_in[18];
    const float* l1_b  = (const float*)d_in[19];
    const float* l2_w  = (const float*)d_in[20];
    const float* l2_b  = (const float*)d_in[21];
    const float* n3_g  = (const float*)d_in[22];
    const float* n3_b  = (const float*)d_in[23];
    const float* fu_w  = (const float*)d_in[24];
    const float* fu_b  = (const float*)d_in[25];
    const float* bn_g  = (const float*)d_in[26];
    const float* bn_b  = (const float*)d_in[27];

    const int N = in_sizes[0] / 64;   // 8192

    float* src   = (float*)d_ws;            // N*128
    float* qs    = src + (size_t)N * 128;   // N*128
    float* ks    = qs  + (size_t)N * 128;   // N*128
    float* vs    = ks  + (size_t)N * 128;   // N*128
    float* fused = vs  + (size_t)N * 128;   // N*64
    int*   nbr    = (int*)(fused + (size_t)N * 64);   // N*16 ints
    float* bnSum  = (float*)(nbr + (size_t)N * 16);   // 64
    float* bnSq   = bnSum + 64;                       // 64 (contiguous 128)

    ka_pre_cst<<<N / 8 + N / 16, 256, 0, stream>>>(features, coords,
                                                   pe_w1, pe_b1, pe_w2, pe_b2,
                                                   in_w, in_b, q_w, k_w, v_w,
                                                   src, qs, ks, vs, nbr, bnSum, N);
    k4_main_cst<<<N / 8, 256, 0, stream>>>(features, src, qs, ks, vs, nbr,
                                           q_b, k_b, v_b, o_w, o_b, n1_g, n1_b,
                                           l1_w, l1_b, l2_w, l2_b, n3_g, n3_b,
                                           fu_w, fu_b, fused, bnSum, bnSq);
    k5_bn_cst<<<512, 256, 0, stream>>>(fused, bnSum, bnSq, bn_g, bn_b,
                                       (float*)d_out, N);
}

// Round 7
// 221.276 us; speedup vs baseline: 1.0974x; 1.0307x over previous
//
#include <hip/hip_runtime.h>

#define DEVFN __device__ __forceinline__

// NaN-propagating relu (fmaxf(NaN,0)==0 would mask upstream failures).
DEVFN float relu(float x) { return x < 0.f ? 0.f : x; }

// ---------------------------------------------------------------------------
// KA: fused pre-work, two block roles interleaved (bx%3): 2/3 src, 1/3 nbr.
//  src role : src = features@in_w+in_b + relu(pe)@pe_w2+pe_b2 ; qs/ks/vs
//  nbr role : neighbor top-16 (manhattan<=4, stable); nbr-block 0 zeros BN.
// __launch_bounds__(256,4): grid gives 4-6 blocks/CU; allow 128 VGPRs.
// ---------------------------------------------------------------------------
__global__ __launch_bounds__(256, 4) void ka_pre_cst(
    const float* __restrict__ features, const int* __restrict__ coords,
    const float* __restrict__ pe_w1, const float* __restrict__ pe_b1,
    const float* __restrict__ pe_w2, const float* __restrict__ pe_b2,
    const float* __restrict__ in_w, const float* __restrict__ in_b,
    const float* __restrict__ q_w, const float* __restrict__ k_w,
    const float* __restrict__ v_w,
    float* __restrict__ src,
    float* __restrict__ qs, float* __restrict__ ks, float* __restrict__ vs,
    int* __restrict__ nbr, float* __restrict__ bnAcc, int N)
{
    // src-role LDS
    __shared__ float sF[512];   // 8 rows x 64 features
    __shared__ float sH[512];   // 8 rows x 64 pe-hidden
    __shared__ float S[1024];   // 8 rows x 128 src
    __shared__ int   sC[24];
    // nbr-role LDS
    __shared__ int cnt[16];
    __shared__ int lst[16 * 64];
    __shared__ int outL[256];

    const int tid = threadIdx.x;
    const int bx = blockIdx.x;
    const int role_nbr = (bx % 3) == 2;

    if (role_nbr) {
        // ---------------- nbr role: neighbor search -----------------------
        const int nb = bx / 3;
        const int q0 = nb * 16;
        if (nb == 0 && tid < 128) bnAcc[tid] = 0.f;
        if (tid < 16) cnt[tid] = 0;
        outL[tid] = -1;
        __syncthreads();
        int qx[16], qy[16], qz[16];
#pragma unroll
        for (int q = 0; q < 16; ++q) {
            qx[q] = coords[(q0 + q) * 3 + 0];
            qy[q] = coords[(q0 + q) * 3 + 1];
            qz[q] = coords[(q0 + q) * 3 + 2];
        }
        for (int cd = tid; cd < N; cd += 256) {
            int cx = coords[cd * 3 + 0];
            int cy = coords[cd * 3 + 1];
            int cz = coords[cd * 3 + 2];
#pragma unroll
            for (int q = 0; q < 16; ++q) {
                int dx = cx - qx[q]; dx = dx < 0 ? -dx : dx;
                int dy = cy - qy[q]; dy = dy < 0 ? -dy : dy;
                int dz = cz - qz[q]; dz = dz < 0 ? -dz : dz;
                int d = dx + dy + dz;
                if (d <= 4) {
                    int s = atomicAdd(&cnt[q], 1);
                    if (s < 64) lst[q * 64 + s] = (d << 13) | cd;
                }
            }
        }
        __syncthreads();
        {
            const int q = tid >> 4, t = tid & 15;
            int n = cnt[q]; if (n > 64) n = 64;
            for (int e = t; e < n; e += 16) {
                int key = lst[q * 64 + e];
                int rank = 0;
                for (int j = 0; j < n; ++j) rank += (lst[q * 64 + j] < key) ? 1 : 0;
                if (rank < 16) outL[q * 16 + rank] = key & 8191;
            }
        }
        __syncthreads();
        {
            const int q = tid >> 4, t = tid & 15;
            nbr[(q0 + q) * 16 + t] = outL[q * 16 + t];
        }
        return;
    }

    // ---------------- src role: src + q/k/v projections -------------------
    const int sb = (bx / 3) * 2 + (bx % 3);   // 0..1023
    const int r0 = sb * 8;
    if (tid < 24) sC[tid] = coords[r0 * 3 + tid];
    for (int i = tid; i < 512; i += 256) sF[i] = features[r0 * 64 + i];
    __syncthreads();
    for (int i = tid; i < 512; i += 256) {
        int r = i >> 6, t = i & 63;
        float v0 = sC[r * 3 + 0] * (1.f / 95.f);
        float v1 = sC[r * 3 + 1] * (1.f / 95.f);
        float v2 = sC[r * 3 + 2] * (1.f / 95.f);
        float h = v0 * pe_w1[t] + v1 * pe_w1[64 + t] + v2 * pe_w1[128 + t] + pe_b1[t];
        sH[i] = relu(h);
    }
    __syncthreads();
    const int c = tid & 127, rh = tid >> 7;
    {
        float acc[4];
        const float base = in_b[c] + pe_b2[c];
#pragma unroll
        for (int r = 0; r < 4; ++r) acc[r] = base;
        for (int j = 0; j < 64; ++j) {
            float w1 = in_w[j * 128 + c];
            float w2 = pe_w2[j * 128 + c];
#pragma unroll
            for (int r = 0; r < 4; ++r) {
                int rr = rh * 4 + r;
                acc[r] += sF[rr * 64 + j] * w1 + sH[rr * 64 + j] * w2;
            }
        }
#pragma unroll
        for (int r = 0; r < 4; ++r) {
            src[(r0 + rh * 4 + r) * 128 + c] = acc[r];
            S[(rh * 4 + r) * 128 + c] = acc[r];
        }
    }
    __syncthreads();
    // q/k/v in one pass: 12 concurrent weight streams for latency hiding
    {
        float aq[4], ak[4], av[4];
#pragma unroll
        for (int r = 0; r < 4; ++r) { aq[r] = 0.f; ak[r] = 0.f; av[r] = 0.f; }
        for (int k4 = 0; k4 < 32; ++k4) {
            float wq0 = q_w[(k4 * 4 + 0) * 128 + c];
            float wq1 = q_w[(k4 * 4 + 1) * 128 + c];
            float wq2 = q_w[(k4 * 4 + 2) * 128 + c];
            float wq3 = q_w[(k4 * 4 + 3) * 128 + c];
            float wk0 = k_w[(k4 * 4 + 0) * 128 + c];
            float wk1 = k_w[(k4 * 4 + 1) * 128 + c];
            float wk2 = k_w[(k4 * 4 + 2) * 128 + c];
            float wk3 = k_w[(k4 * 4 + 3) * 128 + c];
            float wv0 = v_w[(k4 * 4 + 0) * 128 + c];
            float wv1 = v_w[(k4 * 4 + 1) * 128 + c];
            float wv2 = v_w[(k4 * 4 + 2) * 128 + c];
            float wv3 = v_w[(k4 * 4 + 3) * 128 + c];
#pragma unroll
            for (int r = 0; r < 4; ++r) {
                float4 s = *(const float4*)(&S[(rh * 4 + r) * 128 + k4 * 4]);
                aq[r] += s.x * wq0 + s.y * wq1 + s.z * wq2 + s.w * wq3;
                ak[r] += s.x * wk0 + s.y * wk1 + s.z * wk2 + s.w * wk3;
                av[r] += s.x * wv0 + s.y * wv1 + s.z * wv2 + s.w * wv3;
            }
        }
#pragma unroll
        for (int r = 0; r < 4; ++r) {
            qs[(r0 + rh * 4 + r) * 128 + c] = aq[r];
            ks[(r0 + rh * 4 + r) * 128 + c] = ak[r];
            vs[(r0 + rh * 4 + r) * 128 + c] = av[r];
        }
    }
}

// ---------------------------------------------------------------------------
// K4: attention + o-proj + LN1 + FFN + LN2 + fusion + BN partials.
// 8 rows/block, 1024 blocks (4/CU). GEMM phases 2/4 use K-split mapping:
// thread = (col, K-half), 8-row accumulators, LDS reduction — halves the
// per-thread weight-load instruction count vs (col, row-half).
// ---------------------------------------------------------------------------
DEVFN void ln_rows8(float* Cb, const float* __restrict__ g,
                    const float* __restrict__ b, int tid)
{
    const int r = tid >> 5, l = tid & 31;
    float x[4]; float s = 0.f, s2 = 0.f;
#pragma unroll
    for (int i = 0; i < 4; ++i) {
        x[i] = Cb[r * 128 + l * 4 + i];
        s += x[i]; s2 += x[i] * x[i];
    }
#pragma unroll
    for (int o = 1; o < 32; o <<= 1) { s += __shfl_xor(s, o); s2 += __shfl_xor(s2, o); }
    float mu = s * (1.f / 128.f);
    float var = s2 * (1.f / 128.f) - mu * mu;
    float rstd = rsqrtf(var + 1e-5f);
#pragma unroll
    for (int i = 0; i < 4; ++i) {
        int cc = l * 4 + i;
        Cb[r * 128 + cc] = (x[i] - mu) * rstd * g[cc] + b[cc];
    }
}

__global__ __launch_bounds__(256, 4) void k4_main_cst(
    const float* __restrict__ features, const float* __restrict__ src,
    const float* __restrict__ qs, const float* __restrict__ ks, const float* __restrict__ vs,
    const int* __restrict__ nbr,
    const float* __restrict__ q_b, const float* __restrict__ k_b,
    const float* __restrict__ v_b,
    const float* __restrict__ o_w, const float* __restrict__ o_b,
    const float* __restrict__ n1_g, const float* __restrict__ n1_b,
    const float* __restrict__ l1_w, const float* __restrict__ l1_b,
    const float* __restrict__ l2_w, const float* __restrict__ l2_b,
    const float* __restrict__ n3_g, const float* __restrict__ n3_b,
    const float* __restrict__ fu_w, const float* __restrict__ fu_b,
    float* __restrict__ fused, float* __restrict__ bnSum, float* __restrict__ bnSq)
{
    __shared__ float A[1024];           // src tile / phase-4 partial kh=0
    __shared__ float Bt[1024];          // head_out / phase-4 partial kh=1
    __shared__ float C[1024];           // running activation
    __shared__ float Q[1024];           // q rows (bias applied)
    __shared__ float H[2048];           // phase-2 partials / ffn hidden / bn staging
    __shared__ float SC[512];           // attention scores
    __shared__ float F[512];            // features tile
    __shared__ __align__(16) float bK[128], bV[128];
    __shared__ int idxL[128];
    const int tid = threadIdx.x;
    const int r0 = blockIdx.x * 8;

    for (int i = tid; i < 1024; i += 256) A[i] = src[r0 * 128 + i];
    for (int i = tid; i < 512; i += 256) F[i] = features[r0 * 64 + i];
    if (tid < 128) {
        idxL[tid] = nbr[r0 * 16 + tid];
        bK[tid] = k_b[tid]; bV[tid] = v_b[tid];
    }
    __syncthreads();
    {   // vectorized Q gather + bias: thread = (row=tid>>5, colgroup=tid&31)
        int r = tid >> 5, cg = tid & 31;
        int i0 = idxL[r * 16];
        float4 qv = make_float4(0.f, 0.f, 0.f, 0.f);
        if (i0 >= 0) qv = *(const float4*)(qs + i0 * 128 + cg * 4);
        float4 qb = *(const float4*)(q_b + cg * 4);
        qv.x += qb.x; qv.y += qb.y; qv.z += qb.z; qv.w += qb.w;
        *(float4*)(&Q[r * 128 + cg * 4]) = qv;
    }
    __syncthreads();

    // ---- phase 1a: scores. thread = (row r, head h, group g of 8) --------
    const int ar = tid >> 5, ah = (tid >> 3) & 3, ag = tid & 7;
    {
#pragma unroll
        for (int jj = 0; jj < 2; ++jj) {
            int j = ag + jj * 8;
            int j4 = j >> 2, ch = j & 3;
            int id = idxL[ar * 16 + ah * 4 + j4];
            float s = 0.f;
#pragma unroll
            for (int c4 = 0; c4 < 8; ++c4) {
                float4 qv = *(const float4*)(&Q[ar * 128 + ah * 32 + c4 * 4]);
                float4 kb = *(const float4*)(&bK[ch * 32 + c4 * 4]);
                float4 kv = make_float4(0.f, 0.f, 0.f, 0.f);
                if (id >= 0) kv = *(const float4*)(ks + id * 128 + ch * 32 + c4 * 4);
                s += qv.x * (kv.x + kb.x) + qv.y * (kv.y + kb.y)
                   + qv.z * (kv.z + kb.z) + qv.w * (kv.w + kb.w);
            }
            SC[ar * 64 + ah * 16 + j] = s * 0.08838834764831845f;  // 1/sqrt(128)
        }
    }
    __syncthreads();

    // ---- phase 1b: softmax (redundant per 8-thread group) + P@V ----------
    {
        float p[16];
        float mx = -3.4e38f;
#pragma unroll
        for (int j = 0; j < 16; ++j) { p[j] = SC[ar * 64 + ah * 16 + j]; mx = fmaxf(mx, p[j]); }
        float sum = 0.f;
#pragma unroll
        for (int j = 0; j < 16; ++j) { p[j] = __expf(p[j] - mx); sum += p[j]; }
        float inv = 1.f / sum;
        float4 acc = make_float4(0.f, 0.f, 0.f, 0.f);
#pragma unroll
        for (int j = 0; j < 16; ++j) {
            int j4 = j >> 2, ch = j & 3;
            int id = idxL[ar * 16 + ah * 4 + j4];
            float4 vb = *(const float4*)(&bV[ch * 32 + ag * 4]);
            float4 vv = make_float4(0.f, 0.f, 0.f, 0.f);
            if (id >= 0) vv = *(const float4*)(vs + id * 128 + ch * 32 + ag * 4);
            float w = p[j] * inv;
            acc.x += w * (vv.x + vb.x); acc.y += w * (vv.y + vb.y);
            acc.z += w * (vv.z + vb.z); acc.w += w * (vv.w + vb.w);
        }
        *(float4*)(&Bt[ar * 128 + ah * 32 + ag * 4]) = acc;
    }
    __syncthreads();

    // ---- phase 2: out = head_out @ o_w (K-split); C = A + out + o_b ------
    {
        const int c = tid & 127, kh = tid >> 7;
        float acc[8];
#pragma unroll
        for (int r = 0; r < 8; ++r) acc[r] = 0.f;
        const float* wp = o_w + kh * 64 * 128 + c;
        for (int k4 = 0; k4 < 16; ++k4) {
            float w0 = wp[(k4 * 4 + 0) * 128];
            float w1 = wp[(k4 * 4 + 1) * 128];
            float w2 = wp[(k4 * 4 + 2) * 128];
            float w3 = wp[(k4 * 4 + 3) * 128];
#pragma unroll
            for (int r = 0; r < 8; ++r) {
                float4 t = *(const float4*)(&Bt[r * 128 + kh * 64 + k4 * 4]);
                acc[r] += t.x * w0 + t.y * w1 + t.z * w2 + t.w * w3;
            }
        }
#pragma unroll
        for (int r = 0; r < 8; ++r) H[kh * 1024 + r * 128 + c] = acc[r];
    }
    __syncthreads();
    for (int i = tid; i < 1024; i += 256) {
        int c = i & 127;
        C[i] = A[i] + o_b[c] + H[i] + H[1024 + i];
    }
    __syncthreads();
    ln_rows8(C, n1_g, n1_b, tid);   // C = tgt
    __syncthreads();

    // ---- phase 3: H = relu(C @ l1_w + l1_b)  [8 x 256] -------------------
    {
        const int f = tid;
        float acc[8];
#pragma unroll
        for (int r = 0; r < 8; ++r) acc[r] = 0.f;
        for (int k4 = 0; k4 < 32; ++k4) {
            float w0 = l1_w[(k4 * 4 + 0) * 256 + f];
            float w1 = l1_w[(k4 * 4 + 1) * 256 + f];
            float w2 = l1_w[(k4 * 4 + 2) * 256 + f];
            float w3 = l1_w[(k4 * 4 + 3) * 256 + f];
#pragma unroll
            for (int r = 0; r < 8; ++r) {
                float4 t = *(const float4*)(&C[r * 128 + k4 * 4]);
                acc[r] += t.x * w0 + t.y * w1 + t.z * w2 + t.w * w3;
            }
        }
        const float bb = l1_b[f];
#pragma unroll
        for (int r = 0; r < 8; ++r) H[r * 256 + f] = relu(acc[r] + bb);
    }
    __syncthreads();

    // ---- phase 4: t2 = H @ l2_w (K-split, partials in A/Bt); C += t2 -----
    {
        const int c = tid & 127, kh = tid >> 7;
        float acc[8];
#pragma unroll
        for (int r = 0; r < 8; ++r) acc[r] = 0.f;
        const float* wp = l2_w + kh * 128 * 128 + c;
        for (int k4 = 0; k4 < 32; ++k4) {
            float w0 = wp[(k4 * 4 + 0) * 128];
            float w1 = wp[(k4 * 4 + 1) * 128];
            float w2 = wp[(k4 * 4 + 2) * 128];
            float w3 = wp[(k4 * 4 + 3) * 128];
#pragma unroll
            for (int r = 0; r < 8; ++r) {
                float4 t = *(const float4*)(&H[r * 256 + kh * 128 + k4 * 4]);
                acc[r] += t.x * w0 + t.y * w1 + t.z * w2 + t.w * w3;
            }
        }
        float* P = kh ? Bt : A;
#pragma unroll
        for (int r = 0; r < 8; ++r) P[r * 128 + c] = acc[r];
    }
    __syncthreads();
    for (int i = tid; i < 1024; i += 256) {
        int c = i & 127;
        C[i] += l2_b[c] + A[i] + Bt[i];
    }
    __syncthreads();
    ln_rows8(C, n3_g, n3_b, tid);   // C = final tgt
    __syncthreads();

    // ---- phase 5: fused = [F, C] @ fu_w + fu_b; BN partials --------------
    {
        const int c = tid & 63, rg = tid >> 6;
        float acc[2];
        const float fb = fu_b[c];
#pragma unroll
        for (int r = 0; r < 2; ++r) acc[r] = fb;
        for (int j4 = 0; j4 < 16; ++j4) {
            float w0 = fu_w[(j4 * 4 + 0) * 64 + c];
            float w1 = fu_w[(j4 * 4 + 1) * 64 + c];
            float w2 = fu_w[(j4 * 4 + 2) * 64 + c];
            float w3 = fu_w[(j4 * 4 + 3) * 64 + c];
#pragma unroll
            for (int r = 0; r < 2; ++r) {
                float4 t = *(const float4*)(&F[(rg * 2 + r) * 64 + j4 * 4]);
                acc[r] += t.x * w0 + t.y * w1 + t.z * w2 + t.w * w3;
            }
        }
        for (int j4 = 0; j4 < 32; ++j4) {
            float w0 = fu_w[(64 + j4 * 4 + 0) * 64 + c];
            float w1 = fu_w[(64 + j4 * 4 + 1) * 64 + c];
            float w2 = fu_w[(64 + j4 * 4 + 2) * 64 + c];
            float w3 = fu_w[(64 + j4 * 4 + 3) * 64 + c];
#pragma unroll
            for (int r = 0; r < 2; ++r) {
                float4 t = *(const float4*)(&C[(rg * 2 + r) * 128 + j4 * 4]);
                acc[r] += t.x * w0 + t.y * w1 + t.z * w2 + t.w * w3;
            }
        }
#pragma unroll
        for (int r = 0; r < 2; ++r) {
            int row = rg * 2 + r;
            float v = acc[r];
            fused[(r0 + row) * 64 + c] = v;
            H[row * 64 + c] = v;
        }
    }
    __syncthreads();
    if (tid < 64) {
        float s = 0.f, s2 = 0.f;
#pragma unroll
        for (int r = 0; r < 8; ++r) { float x = H[r * 64 + tid]; s += x; s2 += x * x; }
        atomicAdd(&bnSum[tid], s);
        atomicAdd(&bnSq[tid], s2);
    }
}

// ---------------------------------------------------------------------------
// K5: batchnorm (train-mode stats) + relu -> fp32 out
// ---------------------------------------------------------------------------
__global__ __launch_bounds__(256) void k5_bn_cst(
    const float* __restrict__ fused, const float* __restrict__ bnSum,
    const float* __restrict__ bnSq,
    const float* __restrict__ g, const float* __restrict__ b,
    float* __restrict__ out, int N)
{
    const int total = N * 64;
    const float invN = 1.f / (float)N;
    for (int i = blockIdx.x * 256 + threadIdx.x; i < total; i += gridDim.x * 256) {
        int c = i & 63;
        float mu = bnSum[c] * invN;
        float var = bnSq[c] * invN - mu * mu;
        float x = fused[i];
        float y = (x - mu) * rsqrtf(var + 1e-3f) * g[c] + b[c];
        out[i] = relu(y);
    }
}

// ---------------------------------------------------------------------------
extern "C" void kernel_launch(void* const* d_in, const int* in_sizes, int n_in,
                              void* d_out, int out_size, void* d_ws, size_t ws_size,
                              hipStream_t stream)
{
    const float* features = (const float*)d_in[0];
    const int*   coords   = (const int*)d_in[1];
    const float* pe_w1 = (const float*)d_in[2];
    const float* pe_b1 = (const float*)d_in[3];
    const float* pe_w2 = (const float*)d_in[4];
    const float* pe_b2 = (const float*)d_in[5];
    const float* in_w  = (const float*)d_in[6];
    const float* in_b  = (const float*)d_in[7];
    const float* q_w   = (const float*)d_in[8];
    const float* q_b   = (const float*)d_in[9];
    const float* k_w   = (const float*)d_in[10];
    const float* k_b   = (const float*)d_in[11];
    const float* v_w   = (const float*)d_in[12];
    const float* v_b   = (const float*)d_in[13];
    const float* o_w   = (const float*)d_in[14];
    const float* o_b   = (const float*)d_in[15];
    const float* n1_g  = (const float*)d_in[16];
    const float* n1_b  = (const float*)d_in[17];
    const float* l1_w  = (const float*)d_in[18];
    const float* l1_b  = (const float*)d_in[19];
    const float* l2_w  = (const float*)d_in[20];
    const float* l2_b  = (const float*)d_in[21];
    const float* n3_g  = (const float*)d_in[22];
    const float* n3_b  = (const float*)d_in[23];
    const float* fu_w  = (const float*)d_in[24];
    const float* fu_b  = (const float*)d_in[25];
    const float* bn_g  = (const float*)d_in[26];
    const float* bn_b  = (const float*)d_in[27];

    const int N = in_sizes[0] / 64;   // 8192

    float* src   = (float*)d_ws;            // N*128
    float* qs    = src + (size_t)N * 128;   // N*128
    float* ks    = qs  + (size_t)N * 128;   // N*128
    float* vs    = ks  + (size_t)N * 128;   // N*128
    float* fused = vs  + (size_t)N * 128;   // N*64
    int*   nbr    = (int*)(fused + (size_t)N * 64);   // N*16 ints
    float* bnSum  = (float*)(nbr + (size_t)N * 16);   // 64
    float* bnSq   = bnSum + 64;                       // 64 (contiguous 128)

    ka_pre_cst<<<N / 8 + N / 16, 256, 0, stream>>>(features, coords,
                                                   pe_w1, pe_b1, pe_w2, pe_b2,
                                                   in_w, in_b, q_w, k_w, v_w,
                                                   src, qs, ks, vs, nbr, bnSum, N);
    k4_main_cst<<<N / 8, 256, 0, stream>>>(features, src, qs, ks, vs, nbr,
                                           q_b, k_b, v_b, o_w, o_b, n1_g, n1_b,
                                           l1_w, l1_b, l2_w, l2_b, n3_g, n3_b,
                                           fu_w, fu_b, fused, bnSum, bnSq);
    k5_bn_cst<<<512, 256, 0, stream>>>(fused, bnSum, bnSq, bn_g, bn_b,
                                       (float*)d_out, N);
}